// Round 1
// 920.522 us; speedup vs baseline: 1.2925x; 1.2925x over previous
//
#include <hip/hip_runtime.h>
#include <hip/hip_fp16.h>

typedef unsigned int u32;

// Soft-DTW forward, T=4096, D=16, gamma=1. fp32 DP in log2-domain:
// R' = R*log2e; R'[i,j] = d'(i,j) + m - log2(1 + 2^(m-md) + 2^(m-M)),
// m/md/M = min/med/max of (up, diag, left). 64 blocks x 64 lanes, 1 row/lane
// (matches the intrinsic 8192-cell critical path). Skewed wavefront: lane l
// at local step s computes column j = s - l. Intra-band handoff: DPP
// wave_shr1 with old-value passthrough for lane 0 (no cndmask on the chain).
// Band handoff: u32 ring + sentinel + relaxed agent atomics; all lanes load
// the same poll addresses (wave-broadcast, uniform verify).
//
// R4 change: prefetch depth 2 -> 4 groups with STATIC slot rotation
// (group loop unrolled x4, slot = grp%4 = k literal). The old c0<-c1<-n2
// register rotation forced an s_waitcnt on loads issued in the SAME
// iteration (~1 group-time to hide ~1k-cycle cross-XCD latency -> per-group
// stall, amplified 63x by band lag). Now each slot's 9 loads stay in flight
// ~3.9 group-times with zero register moves.

constexpr int   kN      = 4096;
constexpr int   kLanes  = 64;
constexpr int   kBands  = 64;
constexpr int   kSMax   = kN + kLanes;        // 4160
constexpr int   kG      = 8;
constexpr int   kGroups = kSMax / kG;         // 520
constexpr int   kDepth  = 4;                  // prefetch depth (groups), = unroll
constexpr int   kRS     = 4224;               // ring stride (u32): covers (520+4)*8=4192 + slack
constexpr u32   kSent   = 0xFFFFFFFFu;        // NaN pattern, never produced
constexpr float kBig    = 1e10f;
constexpr int   kRowTot = kBands * kRS;
constexpr float kLog2e  = 1.4426950408889634f;
constexpr float kLn2    = 0.6931471805599453f;

#if __has_builtin(__builtin_amdgcn_exp2f)
#define EXP2F(x) __builtin_amdgcn_exp2f(x)
#else
#define EXP2F(x) exp2f(x)
#endif
#if __has_builtin(__builtin_amdgcn_logf)
#define LOG2F(x) __builtin_amdgcn_logf(x)
#else
#define LOG2F(x) log2f(x)
#endif

__device__ __forceinline__ float med3f(float a, float b, float c) {
#if __has_builtin(__builtin_amdgcn_fmed3f)
  return __builtin_amdgcn_fmed3f(a, b, c);
#else
  return fmaxf(fminf(a, b), fminf(fmaxf(a, b), c));
#endif
}

__device__ __forceinline__ float dppShr1fOld(float v, float oldv) {
  // lane l <- lane l-1 (wave_shr1); lane 0 keeps oldv (bound_ctrl=0).
  return __int_as_float(__builtin_amdgcn_update_dpp(
      __float_as_int(oldv), __float_as_int(v), 0x138, 0xF, 0xF, false));
}

__device__ __forceinline__ u32 aload(const u32* p) {
  return __hip_atomic_load(p, __ATOMIC_RELAXED, __HIP_MEMORY_SCOPE_AGENT);
}

// R'-cell: softmin (log2 domain) + pre-scaled distance
__device__ __forceinline__ float cell2(float u, float g, float p, float dpv) {
  const float m  = fminf(fminf(u, g), p);
  const float M  = fmaxf(fmaxf(u, g), p);
  const float md = med3f(u, g, p);
  const float e1 = EXP2F(m - md);
  const float e2 = EXP2F(m - M);
  const float lg = LOG2F(1.0f + e1 + e2);
  return (dpv + m) - lg;
}

__global__ __launch_bounds__(256) void sdtw_prep(const float* __restrict__ A,
                                                 const float* __restrict__ B,
                                                 uint4* __restrict__ Et,
                                                 u32* __restrict__ rowbuf) {
  const int tid = threadIdx.x;
  const int w   = blockIdx.y;
  const int gid = ((w * (int)gridDim.x + (int)blockIdx.x) << 8) + tid;
  if (gid < kRS)          rowbuf[gid] = __float_as_uint(kBig);  // band-0 dummy row
  else if (gid < kRowTot) rowbuf[gid] = kSent;                  // handoff rows + pads

  const int l   = tid & 63;
  const int grp = (int)blockIdx.x * 4 + (tid >> 6);

  const float4* Ap = (const float4*)(A + (size_t)(w * 64 + l) * 16);
  const float4 a0 = Ap[0], a1 = Ap[1], a2 = Ap[2], a3 = Ap[3];
  auto sq = [](float4 a, float4 b) {
    const float dx = a.x - b.x, dy = a.y - b.y, dz = a.z - b.z, dw = a.w - b.w;
    return fmaf(dx, dx, fmaf(dy, dy, fmaf(dz, dz, dw * dw)));
  };
  u32 hp[4];
#pragma unroll
  for (int pr = 0; pr < 4; ++pr) {
    float dv[2];
#pragma unroll
    for (int h = 0; h < 2; ++h) {
      const int q = pr * 2 + h;
      const int s = grp * kG + q + 1;
      const int jb = min(max(s - l - 1, 0), kN - 1);
      const float4* Bp = (const float4*)(B + (size_t)jb * 16);
      dv[h] = (sq(a0, Bp[0]) + sq(a1, Bp[1]) + sq(a2, Bp[2]) + sq(a3, Bp[3])) * kLog2e;
    }
    hp[pr] = ((u32)__half_as_ushort(__float2half(dv[1])) << 16)
           |  (u32)__half_as_ushort(__float2half(dv[0]));
  }
  Et[((size_t)w * kGroups + grp) * 64 + l] = make_uint4(hp[0], hp[1], hp[2], hp[3]);
}

template <bool MASK>
__device__ __forceinline__ void run(int gBeg, int gEnd, int l, int w,
                                    const uint4* __restrict__ EtL,
                                    u32* __restrict__ rowpr, u32* __restrict__ rowme,
                                    float& p, float& dm,
                                    u32 (&c)[kDepth][kG], uint4 (&e)[kDepth],
                                    float* __restrict__ out) {
  const bool isL63 = (l == kLanes - 1);
  const bool wLast = (w == kBands - 1);
  // gBeg/gEnd are multiples of kDepth; slot for group g is g%kDepth == k (static).
  for (int grp = gBeg; grp < gEnd; grp += kDepth) {
#pragma unroll
    for (int k = 0; k < kDepth; ++k) {
      const int g = grp + k;

      // Verify this group's handoff entries (uniform across wave; rare slow path).
      // The s_waitcnt for slot k's loads lands here: they were issued at
      // sub-iter k of the PREVIOUS macro-iteration (~3.9 group-times ago).
      {
        const u32 mA = max(max(c[k][0], c[k][1]), max(c[k][2], c[k][3]));
        const u32 mB = max(max(c[k][4], c[k][5]), max(c[k][6], c[k][7]));
        if (max(mA, mB) == kSent) {
#pragma unroll
          for (int q = 0; q < kG; ++q) {
            const int j = g * kG + 1 + q;
            if (!MASK || j <= kN) {
              u32 v = c[k][q];
              while (v == kSent) v = aload(rowpr + g * kG + q);
              c[k][q] = v;
            }
          }
        }
      }

      const u32 ec[4] = {e[k].x, e[k].y, e[k].z, e[k].w};
#pragma unroll
      for (int q = 0; q < kG; ++q) {
        const int s = g * kG + q + 1;
        // lane l <- lane l-1's p; lane 0 <- handoff entry (DPP old-value path)
        float um = dppShr1fOld(p, __uint_as_float(c[k][q]));

        u32 hw = ec[q >> 1];
        if (q & 1) hw >>= 16;
        const float dpv = __half2float(__ushort_as_half((unsigned short)(hw & 0xFFFFu)));

        float r = cell2(um, dm, p, dpv);
        if (MASK) {
          const int j = s - l;
          r = (j >= 1 && j <= kN) ? r : kBig;
        }
        dm = um; p = r;

        if (!wLast) {
          if (isL63) {
            int idx = s - kLanes;                 // j-1 for lane 63
            if (MASK) {
              const int j = s - (kLanes - 1);
              idx = (j >= 1 && j <= kN) ? idx : kN;   // park invalid in pad
            }
            __hip_atomic_store(rowme + idx, __float_as_uint(r),
                               __ATOMIC_RELAXED, __HIP_MEMORY_SCOPE_AGENT);
          }
        } else if (MASK) {
          if (isL63 && s == kN + kLanes - 1) out[0] = r * kLn2;   // R[4096,4096]
        }
      }

      // Refill slot k for group g+kDepth (in flight until next macro-iter).
      {
        int gn = g + kDepth; if (gn > kGroups - 1) gn = kGroups - 1;
        e[k] = EtL[(size_t)gn * 64];
        const int pbase = (g + kDepth) * kG;      // < kRS by ring padding
#pragma unroll
        for (int q = 0; q < kG; ++q) c[k][q] = aload(rowpr + pbase + q);
      }
    }
  }
}

__global__ __launch_bounds__(kLanes) void sdtw_dp(const uint4* __restrict__ Et,
                                                  u32* __restrict__ rowbuf,
                                                  float* __restrict__ out) {
  const int w = blockIdx.x;
  const int l = threadIdx.x;
  u32* rowpr = rowbuf + (size_t)w * kRS;        // band 0 -> BIG dummy row
  u32* rowme = rowbuf + (size_t)(w + 1) * kRS;  // never stored for last band
  const uint4* EtL = Et + (size_t)w * kGroups * 64 + l;

  float p  = kBig;                               // R'[row, 0] left boundary
  float dm = (w == 0 && l == 0) ? 0.0f : kBig;   // R'[row-1, 0]; R'[0,0]=0

  uint4 e[kDepth];
  u32 c[kDepth][kG];
#pragma unroll
  for (int k = 0; k < kDepth; ++k) {
    e[k] = EtL[(size_t)k * 64];
#pragma unroll
    for (int q = 0; q < kG; ++q) c[k][q] = aload(rowpr + k * kG + q);
  }

  run<true >(0,   8,       l, w, EtL, rowpr, rowme, p, dm, c, e, out);
  run<false>(8,   512,     l, w, EtL, rowpr, rowme, p, dm, c, e, out);
  run<true >(512, kGroups, l, w, EtL, rowpr, rowme, p, dm, c, e, out);
}

extern "C" void kernel_launch(void* const* d_in, const int* in_sizes, int n_in,
                              void* d_out, int out_size, void* d_ws, size_t ws_size,
                              hipStream_t stream) {
  const float* A = (const float*)d_in[0];
  const float* B = (const float*)d_in[1];
  float* out = (float*)d_out;

  u32* rowbuf = (u32*)d_ws;
  uint4* Et = (uint4*)(rowbuf + kRowTot);
  // ws need: 64*4224*4 B + 64*520*64*16 B ~= 1.08 MB + 34.1 MB ~= 35.2 MB

  sdtw_prep<<<dim3(kGroups / 4, kBands), 256, 0, stream>>>(A, B, Et, rowbuf);
  sdtw_dp<<<kBands, kLanes, 0, stream>>>(Et, rowbuf, out);
}